// Round 9
// baseline (292.869 us; speedup 1.0000x reference)
//
#include <hip/hip_runtime.h>

#define NB 4
#define NL 2048
#define NK 30
#define NRES (NB*NL)          // 8192
#define NEDGE (NRES*NK)       // 245760
#define EPB 64                // edges per block in edge_kernel (EPB=128 regressed: VGPR 72, occ 26%)

// ---- workspace layout (float offsets) — total 607,312 floats = 2.43 MB ----
enum : int {
  WOFF_DNB   = 0,        // 245760 f32 (selected D_adjust per edge)
  WOFF_EIDX  = 245760,   // 245760 int32 (selected neighbor per edge)
  WOFF_O     = 491520,   // 73728 (frames, 9 per residue)
  WOFF_WPE   = 565248,   // 1040 (65,16)
  WOFF_BPE   = 566288,   // 16
  WOFF_WCH   = 566304,   // 32
  WOFF_BCH   = 566336,   // 16
  WOFF_WNODE = 566352,   // 384
  WOFF_BNODE = 566736,   // 128
  WOFF_WEDGE = 566864,   // 7040 (55,128) — 16B-aligned for float4
  WOFF_BEDGE = 573904,   // 128
  WOFF_GN    = 574032,   // 128
  WOFF_BNN   = 574160,   // 128
  WOFF_GE    = 574288,   // 128
  WOFF_BNE   = 574416,   // 128
  WOFF_PK    = 574544,   // 32768 = NRES float4 (Ca.x, Ca.y, Ca.z, mask) — 16B aligned
};                        // end 607,312

__device__ __forceinline__ float sgnf(float x) {
  return (x > 0.f) ? 1.f : ((x < 0.f) ? -1.f : 0.f);
}
// runtime float input shim: f32 or bf16 per probe flag
__device__ __forceinline__ float loadf(const void* p, int idx, bool isbf) {
  if (isbf) return __uint_as_float(((unsigned)((const unsigned short*)p)[idx]) << 16);
  return ((const float*)p)[idx];
}
// runtime int input shim: 0=int32, 1=f32, 2=bf16
__device__ __forceinline__ int geti(const void* p, int idx, int mode) {
  if (mode == 0) return ((const int*)p)[idx];
  if (mode == 1) return (int)rintf(((const float*)p)[idx]);
  return (int)rintf(__uint_as_float(((unsigned)((const unsigned short*)p)[idx]) << 16));
}
__device__ __forceinline__ bool probe_bf(const void* maskp) {
  return ((const unsigned*)maskp)[0] == 0x3F803F80u;  // mask all-ones: bf16 pair vs f32
}
__device__ __forceinline__ int probe_int(const void* residxp) {
  unsigned w1 = ((const unsigned*)residxp)[1];        // residue_idx[1] == 1
  return (w1 == 1u) ? 0 : ((w1 == 0x3F800000u) ? 1 : 2);
}
__device__ __forceinline__ unsigned long long shfl_xor_u64(unsigned long long x, int m) {
  int lo = (int)(unsigned)(x & 0xffffffffull);
  int hi = (int)(unsigned)(x >> 32);
  lo = __shfl_xor(lo, m, 64);
  hi = __shfl_xor(hi, m, 64);
  return ((unsigned long long)(unsigned)hi << 32) | (unsigned)lo;
}

struct ConvArgs {
  const void* src[12];
  int off[12];
  int sz[12];
  const void* maskp;
};

// ---------------- kernel A (fused): frames (blocks 0..31) + weight prep (blocks 32..71) ----
__global__ void pf_kernel(ConvArgs a, const void* Xraw, float* wsf) {
  const bool isbf = probe_bf(a.maskp);
  const int t = threadIdx.x;
  if (blockIdx.x < 32) {
    // frames: per-residue local frame O (3x3) + packed Ca/mask
    const int r = blockIdx.x * 256 + t;
    const int xb = r * 12;
    float nx = loadf(Xraw, xb+0, isbf), ny = loadf(Xraw, xb+1, isbf), nz = loadf(Xraw, xb+2, isbf);
    float cax= loadf(Xraw, xb+3, isbf), cay= loadf(Xraw, xb+4, isbf), caz= loadf(Xraw, xb+5, isbf);
    float cx = loadf(Xraw, xb+6, isbf), cy = loadf(Xraw, xb+7, isbf), cz = loadf(Xraw, xb+8, isbf);
    float mk = loadf(a.maskp, r, isbf);
    float4* pko = (float4*)(wsf + WOFF_PK);
    pko[r] = make_float4(cax, cay, caz, mk);
    float v1x=nx-cax, v1y=ny-cay, v1z=nz-caz;
    float v2x=cx-cax, v2y=cy-cay, v2z=cz-caz;
    float n1 = sqrtf(v1x*v1x + v1y*v1y + v1z*v1z) + 1e-6f;
    float e1x=v1x/n1, e1y=v1y/n1, e1z=v1z/n1;
    float dp = e1x*v2x + e1y*v2y + e1z*v2z;
    float u2x=v2x-dp*e1x, u2y=v2y-dp*e1y, u2z=v2z-dp*e1z;
    float n2 = sqrtf(u2x*u2x + u2y*u2y + u2z*u2z) + 1e-6f;
    float e2x=u2x/n2, e2y=u2y/n2, e2z=u2z/n2;
    float e3x = e1y*e2z - e1z*e2y;
    float e3y = e1z*e2x - e1x*e2z;
    float e3z = e1x*e2y - e1y*e2x;
    float* o = wsf + WOFF_O + (size_t)r*9;  // O row-major; cols = e1,e2,e3
    o[0]=e1x; o[1]=e2x; o[2]=e3x;
    o[3]=e1y; o[4]=e2y; o[5]=e3y;
    o[6]=e1z; o[7]=e2z; o[8]=e3z;
  } else {
    // prep: canonicalize the 12 weight arrays to f32
    const int stride = 40 * 256;
    const int t0 = (blockIdx.x - 32) * 256 + t;
    for (int q = 0; q < 12; ++q) {
      float* dst = wsf + a.off[q];
      const int n = a.sz[q];
      for (int i = t0; i < n; i += stride) dst[i] = loadf(a.src[q], i, isbf);
    }
  }
}

// ---------------- topk body: top-30 per row — ONE WAVE PER ROW ----------------
#define CE(i,j) { unsigned long long a_=q[i], b_=q[j]; bool lt_=a_<b_; \
                  q[i]=lt_?a_:b_; q[j]=lt_?b_:a_; }
#define SORT8(B) CE(B+0,B+1) CE(B+2,B+3) CE(B+4,B+5) CE(B+6,B+7) \
                 CE(B+0,B+2) CE(B+1,B+3) CE(B+4,B+6) CE(B+5,B+7) \
                 CE(B+1,B+2) CE(B+5,B+6) \
                 CE(B+0,B+4) CE(B+1,B+5) CE(B+2,B+6) CE(B+3,B+7) \
                 CE(B+2,B+4) CE(B+3,B+5) \
                 CE(B+1,B+2) CE(B+3,B+4) CE(B+5,B+6)
#define SHIFTQ(B) { q[B+0]=q[B+1]; q[B+1]=q[B+2]; q[B+2]=q[B+3]; q[B+3]=q[B+4]; \
                    q[B+4]=q[B+5]; q[B+5]=q[B+6]; q[B+6]=q[B+7]; q[B+7]=~0ull; }

__device__ __forceinline__ void topk_body(int blk, const float* wsf, int* eidx, float* dnb,
                                          float* outf, unsigned long long outEidx) {
#pragma clang fp contract(off)   // bit-match numpy distance for exact top-k ordering
  const int lane = threadIdx.x & 63;
  const int row = blk*4 + (threadIdx.x >> 6);   // one wave per row
  const int b = row >> 11, i = row & (NL-1);
  const float4* pb = ((const float4*)(wsf + WOFF_PK)) + b*NL;
  const float4 pi = pb[i];
  const float xi = pi.x, yi = pi.y, zi = pi.z, mi = pi.w;
  unsigned long long q[32];
  float lmax = -1e30f;
  #pragma unroll
  for (int s=0;s<32;s++){
    float4 pj = pb[s*64 + lane];
    float dx=pj.x-xi, dy=pj.y-yi, dz=pj.z-zi;
    float ss = dx*dx;
    ss = ss + dy*dy;
    ss = ss + dz*dz;
    ss = ss + 1e-6f;
    float m2 = mi*pj.w;
    float d = m2 * sqrtf(ss);              // == 0.0 exactly iff masked (ss >= 1e-6)
    lmax = fmaxf(lmax, d);
    q[s] = ((unsigned long long)__float_as_uint(d) << 32) | (unsigned)(s*64 + lane);
  }
  #pragma unroll
  for (int m=1;m<64;m<<=1) lmax = fmaxf(lmax, __shfl_xor(lmax, m, 64));
  // D_adjust: masked entries (d==0 -> hi word 0) become exactly Dmax (0 + 1.0*Dmax)
  const unsigned dmb = __float_as_uint(lmax);
  #pragma unroll
  for (int s=0;s<32;s++)
    if ((unsigned)(q[s] >> 32) == 0u)
      q[s] = ((unsigned long long)dmb << 32) | (unsigned)q[s];
  // pre-sort 4 queues of 8 (ascending)
  SORT8(0) SORT8(8) SORT8(16) SORT8(24)
  const size_t obase = (size_t)row*NK;
  #pragma unroll 1
  for (int k=0;k<NK;k++){
    unsigned long long c01 = q[0]  < q[8]  ? q[0]  : q[8];
    unsigned long long c23 = q[16] < q[24] ? q[16] : q[24];
    unsigned long long cand = c01 < c23 ? c01 : c23;
    float dh = __uint_as_float((unsigned)(cand >> 32));
    float dmin = dh;
    #pragma unroll
    for (int m=1;m<64;m<<=1) dmin = fminf(dmin, __shfl_xor(dmin, m, 64));
    unsigned long long bal = __ballot(dh == dmin);
    unsigned long long best;
    if (__popcll(bal) == 1) {                // unique distance winner (common case)
      int src = __ffsll((long long)bal) - 1;
      int lo = __shfl((int)(unsigned)cand, src, 64);
      best = ((unsigned long long)__float_as_uint(dmin) << 32) | (unsigned)lo;
    } else {                                 // exact-tie fallback: full u64 butterfly
      best = cand;
      #pragma unroll
      for (int m=1;m<64;m<<=1){
        unsigned long long o2 = shfl_xor_u64(best, m);
        best = o2 < best ? o2 : best;
      }
    }
    if (lane==0){
      unsigned j = (unsigned)best;
      eidx[obase + k] = (int)j;
      dnb[obase + k] = __uint_as_float((unsigned)(best >> 32));
      outf[outEidx + obase + k] = (float)j;   // fused E_idx f32 output
    }
    if (cand == best){                         // exactly one lane (keys unique by j)
      if      (q[0]  == best) SHIFTQ(0)
      else if (q[8]  == best) SHIFTQ(8)
      else if (q[16] == best) SHIFTQ(16)
      else                    SHIFTQ(24)
    }
  }
}

// ---------------- node body: dihedral features -> 3x128 matvec -> LN -> f32 out ----------------
__device__ __forceinline__ void node_body(int blk, const float* wsf, const void* Xraw,
                                          const void* maskp, float* outf) {
  const bool isbf = probe_bf(maskp);
  const int gw = (blk * 256 + (int)threadIdx.x) >> 6;  // one wave per residue
  const int lane = threadIdx.x & 63;
  const int b = gw / NL, l = gw % NL;
  float ad0 = 0.f, ad1 = 0.f, ad2 = 0.f;
  if (l >= 1 && l <= NL - 3) {
    const int base = (b*NL)*12;
    float p0x = loadf(Xraw, base+(l-1)*12+3, isbf), p0y = loadf(Xraw, base+(l-1)*12+4, isbf), p0z = loadf(Xraw, base+(l-1)*12+5, isbf);
    float p1x = loadf(Xraw, base+(l  )*12+3, isbf), p1y = loadf(Xraw, base+(l  )*12+4, isbf), p1z = loadf(Xraw, base+(l  )*12+5, isbf);
    float p2x = loadf(Xraw, base+(l+1)*12+3, isbf), p2y = loadf(Xraw, base+(l+1)*12+4, isbf), p2z = loadf(Xraw, base+(l+1)*12+5, isbf);
    float p3x = loadf(Xraw, base+(l+2)*12+3, isbf), p3y = loadf(Xraw, base+(l+2)*12+4, isbf), p3z = loadf(Xraw, base+(l+2)*12+5, isbf);
    float u2x=p1x-p0x, u2y=p1y-p0y, u2z=p1z-p0z;
    float u1x=p2x-p1x, u1y=p2y-p1y, u1z=p2z-p1z;
    float u0x=p3x-p2x, u0y=p3y-p2y, u0z=p3z-p2z;
    float nn;
    nn = fmaxf(sqrtf(u2x*u2x+u2y*u2y+u2z*u2z), 1e-12f); u2x/=nn; u2y/=nn; u2z/=nn;
    nn = fmaxf(sqrtf(u1x*u1x+u1y*u1y+u1z*u1z), 1e-12f); u1x/=nn; u1y/=nn; u1z/=nn;
    nn = fmaxf(sqrtf(u0x*u0x+u0y*u0y+u0z*u0z), 1e-12f); u0x/=nn; u0y/=nn; u0z/=nn;
    float n2x = u2y*u1z - u2z*u1y, n2y = u2z*u1x - u2x*u1z, n2z = u2x*u1y - u2y*u1x;
    float n1x = u1y*u0z - u1z*u0y, n1y = u1z*u0x - u1x*u0z, n1z = u1x*u0y - u1y*u0x;
    nn = fmaxf(sqrtf(n2x*n2x+n2y*n2y+n2z*n2z), 1e-12f); n2x/=nn; n2y/=nn; n2z/=nn;
    nn = fmaxf(sqrtf(n1x*n1x+n1y*n1y+n1z*n1z), 1e-12f); n1x/=nn; n1y/=nn; n1z/=nn;
    const float lo = (float)(-1.0 + 1e-6), hi = (float)(1.0 - 1e-6);
    float cosA = -(u1x*u0x + u1y*u0y + u1z*u0z);
    cosA = fminf(fmaxf(cosA, lo), hi);
    float A = acosf(cosA);
    float cosD = n2x*n1x + n2y*n1y + n2z*n1z;
    cosD = fminf(fmaxf(cosD, lo), hi);
    float Dd = sgnf(u2x*n1x + u2y*n1y + u2z*n1z) * acosf(cosD);
    ad0 = cosf(A);
    ad1 = sinf(A) * cosf(Dd);
    ad2 = sinf(A) * sinf(Dd);
  }
  const int c0 = 2*lane, c1 = c0 + 1;
  float acc0 = wsf[WOFF_BNODE+c0] + ad0*wsf[WOFF_WNODE+c0] + ad1*wsf[WOFF_WNODE+128+c0] + ad2*wsf[WOFF_WNODE+256+c0];
  float acc1 = wsf[WOFF_BNODE+c1] + ad0*wsf[WOFF_WNODE+c1] + ad1*wsf[WOFF_WNODE+128+c1] + ad2*wsf[WOFF_WNODE+256+c1];
  float s = acc0 + acc1;
  for (int m=1;m<64;m<<=1) s += __shfl_xor(s, m, 64);
  float mu_ = s * (1.0f/128.0f);
  float d0 = acc0 - mu_, d1 = acc1 - mu_;
  float v = d0*d0 + d1*d1;
  for (int m=1;m<64;m<<=1) v += __shfl_xor(v, m, 64);
  float inv = 1.0f / sqrtf(v * (1.0f/128.0f) + 1e-5f);
  float y0 = d0*inv*wsf[WOFF_GN + c0] + wsf[WOFF_BNN + c0];
  float y1 = d1*inv*wsf[WOFF_GN + c1] + wsf[WOFF_BNN + c1];
  float2 pk; pk.x = y0; pk.y = y1;
  *((float2*)(outf + (size_t)gw*128 + c0)) = pk;
}

// ---------------- kernel B (fused): topk (blocks 0..2047) + node (blocks 2048..4095) ----
// __launch_bounds__(256, 4): cap VGPR at 128 (live set ~104: q[32]=64 + temps) so the
// scheduler fits 4 waves/SIMD. Without it the fully-unrolled 32x float4 distance-load
// pipeline can push allocation past 128 -> 2 waves/SIMD -> the 30 serial shuffle rounds
// run latency-exposed. Cap is well above live set -> no spill (R4 lesson).
__global__ __launch_bounds__(256, 4) void tn_kernel(const float* wsf, int* eidx, float* dnb,
                                                 float* outf, unsigned long long outEidx,
                                                 const void* Xraw, const void* maskp) {
  if (blockIdx.x < NRES/4) topk_body(blockIdx.x, wsf, eidx, dnb, outf, outEidx);
  else                     node_body(blockIdx.x - NRES/4, wsf, Xraw, maskp, outf);
}

// ---- kernel C: edge features -> 55x128 matvec (64 edges/block) -> LN -> f32 out ----
// R6-proven config: lane owns 4 edges (eg) x 8 cols (cg); W from global (L1-hot 28 KB);
// LDS only F (14 KB); VGPR ~40 -> occ ~53%, 88 us. EPB=128 variant regressed (VGPR 72).
__global__ __launch_bounds__(256) void edge_kernel(const float* wsf, const int* eidx,
                                                   const void* Xraw, const void* maskp,
                                                   const void* residx, const void* chains,
                                                   float* outf, unsigned long long outE) {
  __shared__ float F[55][EPB];     // 14080 B — features, [d][edge]
  const bool isbf = probe_bf(maskp);
  const int icmode = probe_int(residx);
  const int t = threadIdx.x;
  // phase 1: feature construction — g = lane (edge), sq = wave (row group):
  // wave sq writes rows {4sq..4sq+3} of each 16-row class for all 64 edges; conflict-free.
  const int g = t & 63, sq = t >> 6;
  const int e = blockIdx.x * EPB + g;
  const int row = e / NK;
  const int b = row / NL, i = row % NL;
  const int j = eidx[e];
  const int ri = geti(residx, b*NL + i, icmode), rj = geti(residx, b*NL + j, icmode);
  int dd = rj - ri + 32;
  dd = dd < 0 ? 0 : (dd > 64 ? 64 : dd);
  const int ci = geti(chains, b*NL + i, icmode), cj = geti(chains, b*NL + j, icmode);
  const float D = wsf[WOFF_DNB + e];
  #pragma unroll
  for (int u = 0; u < 4; ++u) {
    const int s = sq*4 + u;   // 0..15
    // positional (rows 0..15)
    F[s][g] = wsf[WOFF_WPE + dd*16 + s] + wsf[WOFF_BPE + s];
    // RBF (rows 16..31)
    float mu = (float)(2.0 + s * (20.0 / 15.0));
    float tt = (D - mu) / 1.25f;
    F[16+s][g] = expf(-(tt*tt));
    // chains (rows 39..54)
    float w = (ci == cj) ? wsf[WOFF_WCH + s] : wsf[WOFF_WCH + 16 + s];
    F[39+s][g] = w + wsf[WOFF_BCH + s];
  }
  if (g < 16) {  // dU + quaternion (rows 32..38): wave sq handles edges sq*16..sq*16+15
    const int gq = sq*16 + g;
    const int eq = blockIdx.x * EPB + gq;
    const int rowq = eq / NK;
    const int bq = rowq / NL;
    const int jq = eidx[eq];
    const float* Oi = wsf + WOFF_O + (size_t)rowq*9;
    const float* Oj = wsf + WOFF_O + ((size_t)(bq*NL + jq))*9;
    const int ci_ = rowq*12 + 3, cj_ = (bq*NL + jq)*12 + 3;
    float dx = loadf(Xraw, cj_+0, isbf) - loadf(Xraw, ci_+0, isbf);
    float dy = loadf(Xraw, cj_+1, isbf) - loadf(Xraw, ci_+1, isbf);
    float dz = loadf(Xraw, cj_+2, isbf) - loadf(Xraw, ci_+2, isbf);
    float du0 = Oi[0]*dx + Oi[1]*dy + Oi[2]*dz;
    float du1 = Oi[3]*dx + Oi[4]*dy + Oi[5]*dz;
    float du2 = Oi[6]*dx + Oi[7]*dy + Oi[8]*dz;
    float n = fmaxf(sqrtf(du0*du0 + du1*du1 + du2*du2), 1e-12f);
    F[32][gq] = du0/n; F[33][gq] = du1/n; F[34][gq] = du2/n;
    float R[3][3];
    #pragma unroll
    for (int a2=0;a2<3;a2++)
      #pragma unroll
      for (int m=0;m<3;m++)
        R[a2][m] = Oi[0*3+a2]*Oj[0*3+m] + Oi[1*3+a2]*Oj[1*3+m] + Oi[2*3+a2]*Oj[2*3+m];
    float mx = 0.5f*sqrtf(fabsf(1.0f + R[0][0] - R[1][1] - R[2][2]));
    float my = 0.5f*sqrtf(fabsf(1.0f - R[0][0] + R[1][1] - R[2][2]));
    float mz = 0.5f*sqrtf(fabsf(1.0f - R[0][0] - R[1][1] + R[2][2]));
    float qx = sgnf(R[2][1]-R[1][2]) * mx;
    float qy = sgnf(R[0][2]-R[2][0]) * my;
    float qz = sgnf(R[1][0]-R[0][1]) * mz;
    float qw = sqrtf(fmaxf(1.0f + R[0][0] + R[1][1] + R[2][2], 0.0f)) / 2.0f;
    float qn = fmaxf(sqrtf(qx*qx + qy*qy + qz*qz + qw*qw), 1e-12f);
    F[35][gq] = qx/qn; F[36][gq] = qy/qn; F[37][gq] = qz/qn; F[38][gq] = qw/qn;
  }
  __syncthreads();
  // phase 2: wave wv -> edges wv*16..wv*16+15; lane owns 4 edges (eg) x 8 cols (cg)
  const int wv = t >> 6, lane = t & 63;
  const int eg = lane >> 4;          // edge sub-group 0..3
  const int cg = lane & 15;          // col group 0..15
  const int ebase = wv*16 + eg*4;    // block-local first edge of this lane's 4
  const int c0 = cg*8;               // first col of this lane's 8
  const float4* W4 = (const float4*)(wsf + WOFF_WEDGE);   // [55][32] float4, L1-hot
  const float4 beA = *(const float4*)(wsf + WOFF_BEDGE + c0);
  const float4 beB = *(const float4*)(wsf + WOFF_BEDGE + c0 + 4);
  float acc[4][8];
  #pragma unroll
  for (int qq=0;qq<4;qq++){
    acc[qq][0]=beA.x; acc[qq][1]=beA.y; acc[qq][2]=beA.z; acc[qq][3]=beA.w;
    acc[qq][4]=beB.x; acc[qq][5]=beB.y; acc[qq][6]=beB.z; acc[qq][7]=beB.w;
  }
  for (int d = 0; d < 55; ++d) {
    float4 f  = *(const float4*)&F[d][ebase];   // 1 ds_read_b128, 4-addr broadcast
    float4 wa = W4[d*32 + cg*2];                // cols c0..c0+3 (global, L1)
    float4 wb = W4[d*32 + cg*2 + 1];            // cols c0+4..c0+7
    #pragma unroll
    for (int qq=0;qq<4;qq++){
      float fq = (qq==0)?f.x:(qq==1)?f.y:(qq==2)?f.z:f.w;
      acc[qq][0] = fmaf(fq, wa.x, acc[qq][0]);
      acc[qq][1] = fmaf(fq, wa.y, acc[qq][1]);
      acc[qq][2] = fmaf(fq, wa.z, acc[qq][2]);
      acc[qq][3] = fmaf(fq, wa.w, acc[qq][3]);
      acc[qq][4] = fmaf(fq, wb.x, acc[qq][4]);
      acc[qq][5] = fmaf(fq, wb.y, acc[qq][5]);
      acc[qq][6] = fmaf(fq, wb.z, acc[qq][6]);
      acc[qq][7] = fmaf(fq, wb.w, acc[qq][7]);
    }
  }
  const float4 geA = *(const float4*)(wsf + WOFF_GE + c0);
  const float4 geB = *(const float4*)(wsf + WOFF_GE + c0 + 4);
  const float4 bnA = *(const float4*)(wsf + WOFF_BNE + c0);
  const float4 bnB = *(const float4*)(wsf + WOFF_BNE + c0 + 4);
  #pragma unroll
  for (int qq=0;qq<4;qq++){
    float s = ((acc[qq][0]+acc[qq][1])+(acc[qq][2]+acc[qq][3]))
            + ((acc[qq][4]+acc[qq][5])+(acc[qq][6]+acc[qq][7]));
    // butterfly over the 16-lane col group (lanes share eg; xor<16 stays in group)
    s += __shfl_xor(s, 1, 64); s += __shfl_xor(s, 2, 64);
    s += __shfl_xor(s, 4, 64); s += __shfl_xor(s, 8, 64);
    float mu_ = s * (1.0f/128.0f);
    float dv[8];
    #pragma unroll
    for (int jj=0;jj<8;jj++) dv[jj] = acc[qq][jj] - mu_;
    float v = ((dv[0]*dv[0]+dv[1]*dv[1])+(dv[2]*dv[2]+dv[3]*dv[3]))
            + ((dv[4]*dv[4]+dv[5]*dv[5])+(dv[6]*dv[6]+dv[7]*dv[7]));
    v += __shfl_xor(v, 1, 64); v += __shfl_xor(v, 2, 64);
    v += __shfl_xor(v, 4, 64); v += __shfl_xor(v, 8, 64);
    float inv = 1.0f / sqrtf(v * (1.0f/128.0f) + 1e-5f);
    float4 oA, oB;
    oA.x = dv[0]*inv*geA.x + bnA.x; oA.y = dv[1]*inv*geA.y + bnA.y;
    oA.z = dv[2]*inv*geA.z + bnA.z; oA.w = dv[3]*inv*geA.w + bnA.w;
    oB.x = dv[4]*inv*geB.x + bnB.x; oB.y = dv[5]*inv*geB.y + bnB.y;
    oB.z = dv[6]*inv*geB.z + bnB.z; oB.w = dv[7]*inv*geB.w + bnB.w;
    float* op = outf + outE + (size_t)(blockIdx.x*EPB + ebase + qq)*128 + c0;
    *(float4*)op       = oA;
    *(float4*)(op + 4) = oB;
  }
}

extern "C" void kernel_launch(void* const* d_in, const int* in_sizes, int n_in,
                              void* d_out, int out_size, void* d_ws, size_t ws_size,
                              hipStream_t stream) {
  float* wsf = (float*)d_ws;
  int* eidx = (int*)(wsf + WOFF_EIDX);
  float* dnb = wsf + WOFF_DNB;
  float* outf = (float*)d_out;   // output is FLOAT32 (confirmed r4)
  const void* Xraw = d_in[0];
  const void* maskp = d_in[1];

  unsigned long long outEidx = (unsigned long long)out_size - NEDGE;
  unsigned long long outE    = outEidx - (unsigned long long)NEDGE*128;

  ConvArgs ca;
  const int fsz[12]  = {1040, 16, 32, 16, 384, 128, 7040, 128, 128, 128, 128, 128};
  const int foff[12] = {WOFF_WPE, WOFF_BPE, WOFF_WCH, WOFF_BCH, WOFF_WNODE, WOFF_BNODE,
                        WOFF_WEDGE, WOFF_BEDGE, WOFF_GN, WOFF_BNN, WOFF_GE, WOFF_BNE};
  for (int q = 0; q < 12; ++q) { ca.src[q] = d_in[4 + q]; ca.off[q] = foff[q]; ca.sz[q] = fsz[q]; }
  ca.maskp = maskp;

  pf_kernel<<<72, 256, 0, stream>>>(ca, Xraw, wsf);
  tn_kernel<<<NRES/4 + NRES/4, 256, 0, stream>>>(wsf, eidx, dnb, outf, outEidx, Xraw, maskp);
  edge_kernel<<<NEDGE/EPB, 256, 0, stream>>>(wsf, eidx, Xraw, maskp, d_in[2], d_in[3], outf, outE);
}

// Round 10
// 271.058 us; speedup vs baseline: 1.0805x; 1.0805x over previous
//
#include <hip/hip_runtime.h>

#define NB 4
#define NL 2048
#define NK 30
#define NRES (NB*NL)          // 8192
#define NEDGE (NRES*NK)       // 245760
#define EPB 64                // edges per block in edge_kernel
#define KD 23                 // matvec depth after folding pos+chains into P2/C2 lookups

// ---- workspace layout (float offsets) — total 615,888 floats = 2.46 MB ----
enum : int {
  WOFF_DNB   = 0,        // 245760 f32 (selected D_adjust per edge)
  WOFF_EIDX  = 245760,   // 245760 int32 (selected neighbor per edge)
  WOFF_O     = 491520,   // 73728 (frames, 9 per residue)
  WOFF_WPE   = 565248,   // 1040 (65,16)
  WOFF_BPE   = 566288,   // 16
  WOFF_WCH   = 566304,   // 32
  WOFF_BCH   = 566336,   // 16
  WOFF_WNODE = 566352,   // 384
  WOFF_BNODE = 566736,   // 128
  WOFF_WEDGE = 566864,   // 7040 (55,128) — 16B-aligned for float4
  WOFF_BEDGE = 573904,   // 128
  WOFF_GN    = 574032,   // 128
  WOFF_BNN   = 574160,   // 128
  WOFF_GE    = 574288,   // 128
  WOFF_BNE   = 574416,   // 128
  WOFF_PK    = 574544,   // 32768 = NRES float4 (Ca.x, Ca.y, Ca.z, mask) — 16B aligned
  WOFF_P2    = 607312,   // 8320 = 65x128: (W_pe[dd]+b_pe) @ W_edge[0:16] + b_edge
  WOFF_C2    = 615632,   // 256 = 2x128: (W_ch[k]+b_ch) @ W_edge[39:55]
};                        // end 615,888

__device__ __forceinline__ float sgnf(float x) {
  return (x > 0.f) ? 1.f : ((x < 0.f) ? -1.f : 0.f);
}
// runtime float input shim: f32 or bf16 per probe flag
__device__ __forceinline__ float loadf(const void* p, int idx, bool isbf) {
  if (isbf) return __uint_as_float(((unsigned)((const unsigned short*)p)[idx]) << 16);
  return ((const float*)p)[idx];
}
// runtime int input shim: 0=int32, 1=f32, 2=bf16
__device__ __forceinline__ int geti(const void* p, int idx, int mode) {
  if (mode == 0) return ((const int*)p)[idx];
  if (mode == 1) return (int)rintf(((const float*)p)[idx]);
  return (int)rintf(__uint_as_float(((unsigned)((const unsigned short*)p)[idx]) << 16));
}
__device__ __forceinline__ bool probe_bf(const void* maskp) {
  return ((const unsigned*)maskp)[0] == 0x3F803F80u;  // mask all-ones: bf16 pair vs f32
}
__device__ __forceinline__ int probe_int(const void* residxp) {
  unsigned w1 = ((const unsigned*)residxp)[1];        // residue_idx[1] == 1
  return (w1 == 1u) ? 0 : ((w1 == 0x3F800000u) ? 1 : 2);
}
__device__ __forceinline__ unsigned long long shfl_xor_u64(unsigned long long x, int m) {
  int lo = (int)(unsigned)(x & 0xffffffffull);
  int hi = (int)(unsigned)(x >> 32);
  lo = __shfl_xor(lo, m, 64);
  hi = __shfl_xor(hi, m, 64);
  return ((unsigned long long)(unsigned)hi << 32) | (unsigned)lo;
}

struct ConvArgs {
  const void* src[12];
  int off[12];
  int sz[12];
  const void* maskp;
};

// ---- kernel A (fused): frames (0..31) + weight prep (32..71) + P2/C2 fold tables (72..105) ----
__global__ void pf_kernel(ConvArgs a, const void* Xraw, float* wsf) {
  const bool isbf = probe_bf(a.maskp);
  const int t = threadIdx.x;
  if (blockIdx.x < 32) {
    // frames: per-residue local frame O (3x3) + packed Ca/mask
    const int r = blockIdx.x * 256 + t;
    const int xb = r * 12;
    float nx = loadf(Xraw, xb+0, isbf), ny = loadf(Xraw, xb+1, isbf), nz = loadf(Xraw, xb+2, isbf);
    float cax= loadf(Xraw, xb+3, isbf), cay= loadf(Xraw, xb+4, isbf), caz= loadf(Xraw, xb+5, isbf);
    float cx = loadf(Xraw, xb+6, isbf), cy = loadf(Xraw, xb+7, isbf), cz = loadf(Xraw, xb+8, isbf);
    float mk = loadf(a.maskp, r, isbf);
    float4* pko = (float4*)(wsf + WOFF_PK);
    pko[r] = make_float4(cax, cay, caz, mk);
    float v1x=nx-cax, v1y=ny-cay, v1z=nz-caz;
    float v2x=cx-cax, v2y=cy-cay, v2z=cz-caz;
    float n1 = sqrtf(v1x*v1x + v1y*v1y + v1z*v1z) + 1e-6f;
    float e1x=v1x/n1, e1y=v1y/n1, e1z=v1z/n1;
    float dp = e1x*v2x + e1y*v2y + e1z*v2z;
    float u2x=v2x-dp*e1x, u2y=v2y-dp*e1y, u2z=v2z-dp*e1z;
    float n2 = sqrtf(u2x*u2x + u2y*u2y + u2z*u2z) + 1e-6f;
    float e2x=u2x/n2, e2y=u2y/n2, e2z=u2z/n2;
    float e3x = e1y*e2z - e1z*e2y;
    float e3y = e1z*e2x - e1x*e2z;
    float e3z = e1x*e2y - e1y*e2x;
    float* o = wsf + WOFF_O + (size_t)r*9;  // O row-major; cols = e1,e2,e3
    o[0]=e1x; o[1]=e2x; o[2]=e3x;
    o[3]=e1y; o[4]=e2y; o[5]=e3y;
    o[6]=e1z; o[7]=e2z; o[8]=e3z;
  } else if (blockIdx.x < 72) {
    // prep: canonicalize the 12 weight arrays to f32
    const int stride = 40 * 256;
    const int t0 = (blockIdx.x - 32) * 256 + t;
    for (int q = 0; q < 12; ++q) {
      float* dst = wsf + a.off[q];
      const int n = a.sz[q];
      for (int i = t0; i < n; i += stride) dst[i] = loadf(a.src[q], i, isbf);
    }
  } else {
    // fold tables, straight from raw inputs (no intra-grid dependency):
    // P2[dd][c] = b_edge[c] + sum_s (W_pe[dd][s]+b_pe[s]) * W_edge[s][c]
    // C2[k][c]  = sum_s (W_ch[k][s]+b_ch[s]) * W_edge[39+s][c]
    const int o = (blockIdx.x - 72) * 256 + t;
    if (o < 65*128) {
      const int dd = o >> 7, c = o & 127;
      float sum = loadf(a.src[7], c, isbf);          // b_edge folded in
      #pragma unroll
      for (int s = 0; s < 16; ++s)
        sum += (loadf(a.src[0], dd*16 + s, isbf) + loadf(a.src[1], s, isbf))
               * loadf(a.src[6], s*128 + c, isbf);
      wsf[WOFF_P2 + o] = sum;
    } else if (o < 65*128 + 256) {
      const int idx = o - 65*128;
      const int k = idx >> 7, c = idx & 127;
      float sum = 0.f;
      #pragma unroll
      for (int s = 0; s < 16; ++s)
        sum += (loadf(a.src[2], k*16 + s, isbf) + loadf(a.src[3], s, isbf))
               * loadf(a.src[6], (39+s)*128 + c, isbf);
      wsf[WOFF_C2 + idx] = sum;
    }
  }
}

// ---------------- topk body: top-30 per row — ONE WAVE PER ROW ----------------
#define CE(i,j) { unsigned long long a_=q[i], b_=q[j]; bool lt_=a_<b_; \
                  q[i]=lt_?a_:b_; q[j]=lt_?b_:a_; }
#define SORT8(B) CE(B+0,B+1) CE(B+2,B+3) CE(B+4,B+5) CE(B+6,B+7) \
                 CE(B+0,B+2) CE(B+1,B+3) CE(B+4,B+6) CE(B+5,B+7) \
                 CE(B+1,B+2) CE(B+5,B+6) \
                 CE(B+0,B+4) CE(B+1,B+5) CE(B+2,B+6) CE(B+3,B+7) \
                 CE(B+2,B+4) CE(B+3,B+5) \
                 CE(B+1,B+2) CE(B+3,B+4) CE(B+5,B+6)
#define SHIFTQ(B) { q[B+0]=q[B+1]; q[B+1]=q[B+2]; q[B+2]=q[B+3]; q[B+3]=q[B+4]; \
                    q[B+4]=q[B+5]; q[B+5]=q[B+6]; q[B+6]=q[B+7]; q[B+7]=~0ull; }

__device__ __forceinline__ void topk_body(int blk, const float* wsf, int* eidx, float* dnb,
                                          float* outf, unsigned long long outEidx) {
#pragma clang fp contract(off)   // bit-match numpy distance for exact top-k ordering
  const int lane = threadIdx.x & 63;
  const int row = blk*4 + (threadIdx.x >> 6);   // one wave per row
  const int b = row >> 11, i = row & (NL-1);
  const float4* pb = ((const float4*)(wsf + WOFF_PK)) + b*NL;
  const float4 pi = pb[i];
  const float xi = pi.x, yi = pi.y, zi = pi.z, mi = pi.w;
  unsigned long long q[32];
  float lmax = -1e30f;
  #pragma unroll
  for (int s=0;s<32;s++){
    float4 pj = pb[s*64 + lane];
    float dx=pj.x-xi, dy=pj.y-yi, dz=pj.z-zi;
    float ss = dx*dx;
    ss = ss + dy*dy;
    ss = ss + dz*dz;
    ss = ss + 1e-6f;
    float m2 = mi*pj.w;
    float d = m2 * sqrtf(ss);              // == 0.0 exactly iff masked (ss >= 1e-6)
    lmax = fmaxf(lmax, d);
    q[s] = ((unsigned long long)__float_as_uint(d) << 32) | (unsigned)(s*64 + lane);
  }
  #pragma unroll
  for (int m=1;m<64;m<<=1) lmax = fmaxf(lmax, __shfl_xor(lmax, m, 64));
  // D_adjust: masked entries (d==0 -> hi word 0) become exactly Dmax (0 + 1.0*Dmax)
  const unsigned dmb = __float_as_uint(lmax);
  #pragma unroll
  for (int s=0;s<32;s++)
    if ((unsigned)(q[s] >> 32) == 0u)
      q[s] = ((unsigned long long)dmb << 32) | (unsigned)q[s];
  // pre-sort 4 queues of 8 (ascending)
  SORT8(0) SORT8(8) SORT8(16) SORT8(24)
  const size_t obase = (size_t)row*NK;
  #pragma unroll 1
  for (int k=0;k<NK;k++){
    unsigned long long c01 = q[0]  < q[8]  ? q[0]  : q[8];
    unsigned long long c23 = q[16] < q[24] ? q[16] : q[24];
    unsigned long long cand = c01 < c23 ? c01 : c23;
    float dh = __uint_as_float((unsigned)(cand >> 32));
    float dmin = dh;
    #pragma unroll
    for (int m=1;m<64;m<<=1) dmin = fminf(dmin, __shfl_xor(dmin, m, 64));
    unsigned long long bal = __ballot(dh == dmin);
    unsigned long long best;
    if (__popcll(bal) == 1) {                // unique distance winner (common case)
      int src = __ffsll((long long)bal) - 1;
      int lo = __shfl((int)(unsigned)cand, src, 64);
      best = ((unsigned long long)__float_as_uint(dmin) << 32) | (unsigned)lo;
    } else {                                 // exact-tie fallback: full u64 butterfly
      best = cand;
      #pragma unroll
      for (int m=1;m<64;m<<=1){
        unsigned long long o2 = shfl_xor_u64(best, m);
        best = o2 < best ? o2 : best;
      }
    }
    if (lane==0){
      unsigned j = (unsigned)best;
      eidx[obase + k] = (int)j;
      dnb[obase + k] = __uint_as_float((unsigned)(best >> 32));
      outf[outEidx + obase + k] = (float)j;   // fused E_idx f32 output
    }
    if (cand == best){                         // exactly one lane (keys unique by j)
      if      (q[0]  == best) SHIFTQ(0)
      else if (q[8]  == best) SHIFTQ(8)
      else if (q[16] == best) SHIFTQ(16)
      else                    SHIFTQ(24)
    }
  }
}

// ---------------- node body: dihedral features -> 3x128 matvec -> LN -> f32 out ----------------
__device__ __forceinline__ void node_body(int blk, const float* wsf, const void* Xraw,
                                          const void* maskp, float* outf) {
  const bool isbf = probe_bf(maskp);
  const int gw = (blk * 256 + (int)threadIdx.x) >> 6;  // one wave per residue
  const int lane = threadIdx.x & 63;
  const int b = gw / NL, l = gw % NL;
  float ad0 = 0.f, ad1 = 0.f, ad2 = 0.f;
  if (l >= 1 && l <= NL - 3) {
    const int base = (b*NL)*12;
    float p0x = loadf(Xraw, base+(l-1)*12+3, isbf), p0y = loadf(Xraw, base+(l-1)*12+4, isbf), p0z = loadf(Xraw, base+(l-1)*12+5, isbf);
    float p1x = loadf(Xraw, base+(l  )*12+3, isbf), p1y = loadf(Xraw, base+(l  )*12+4, isbf), p1z = loadf(Xraw, base+(l  )*12+5, isbf);
    float p2x = loadf(Xraw, base+(l+1)*12+3, isbf), p2y = loadf(Xraw, base+(l+1)*12+4, isbf), p2z = loadf(Xraw, base+(l+1)*12+5, isbf);
    float p3x = loadf(Xraw, base+(l+2)*12+3, isbf), p3y = loadf(Xraw, base+(l+2)*12+4, isbf), p3z = loadf(Xraw, base+(l+2)*12+5, isbf);
    float u2x=p1x-p0x, u2y=p1y-p0y, u2z=p1z-p0z;
    float u1x=p2x-p1x, u1y=p2y-p1y, u1z=p2z-p1z;
    float u0x=p3x-p2x, u0y=p3y-p2y, u0z=p3z-p2z;
    float nn;
    nn = fmaxf(sqrtf(u2x*u2x+u2y*u2y+u2z*u2z), 1e-12f); u2x/=nn; u2y/=nn; u2z/=nn;
    nn = fmaxf(sqrtf(u1x*u1x+u1y*u1y+u1z*u1z), 1e-12f); u1x/=nn; u1y/=nn; u1z/=nn;
    nn = fmaxf(sqrtf(u0x*u0x+u0y*u0y+u0z*u0z), 1e-12f); u0x/=nn; u0y/=nn; u0z/=nn;
    float n2x = u2y*u1z - u2z*u1y, n2y = u2z*u1x - u2x*u1z, n2z = u2x*u1y - u2y*u1x;
    float n1x = u1y*u0z - u1z*u0y, n1y = u1z*u0x - u1x*u0z, n1z = u1x*u0y - u1y*u0x;
    nn = fmaxf(sqrtf(n2x*n2x+n2y*n2y+n2z*n2z), 1e-12f); n2x/=nn; n2y/=nn; n2z/=nn;
    nn = fmaxf(sqrtf(n1x*n1x+n1y*n1y+n1z*n1z), 1e-12f); n1x/=nn; n1y/=nn; n1z/=nn;
    const float lo = (float)(-1.0 + 1e-6), hi = (float)(1.0 - 1e-6);
    float cosA = -(u1x*u0x + u1y*u0y + u1z*u0z);
    cosA = fminf(fmaxf(cosA, lo), hi);
    float A = acosf(cosA);
    float cosD = n2x*n1x + n2y*n1y + n2z*n1z;
    cosD = fminf(fmaxf(cosD, lo), hi);
    float Dd = sgnf(u2x*n1x + u2y*n1y + u2z*n1z) * acosf(cosD);
    ad0 = cosf(A);
    ad1 = sinf(A) * cosf(Dd);
    ad2 = sinf(A) * sinf(Dd);
  }
  const int c0 = 2*lane, c1 = c0 + 1;
  float acc0 = wsf[WOFF_BNODE+c0] + ad0*wsf[WOFF_WNODE+c0] + ad1*wsf[WOFF_WNODE+128+c0] + ad2*wsf[WOFF_WNODE+256+c0];
  float acc1 = wsf[WOFF_BNODE+c1] + ad0*wsf[WOFF_WNODE+c1] + ad1*wsf[WOFF_WNODE+128+c1] + ad2*wsf[WOFF_WNODE+256+c1];
  float s = acc0 + acc1;
  for (int m=1;m<64;m<<=1) s += __shfl_xor(s, m, 64);
  float mu_ = s * (1.0f/128.0f);
  float d0 = acc0 - mu_, d1 = acc1 - mu_;
  float v = d0*d0 + d1*d1;
  for (int m=1;m<64;m<<=1) v += __shfl_xor(v, m, 64);
  float inv = 1.0f / sqrtf(v * (1.0f/128.0f) + 1e-5f);
  float y0 = d0*inv*wsf[WOFF_GN + c0] + wsf[WOFF_BNN + c0];
  float y1 = d1*inv*wsf[WOFF_GN + c1] + wsf[WOFF_BNN + c1];
  float2 pk; pk.x = y0; pk.y = y1;
  *((float2*)(outf + (size_t)gw*128 + c0)) = pk;
}

// ---------------- kernel B (fused): topk (blocks 0..2047) + node (blocks 2048..4095) ----
__global__ __launch_bounds__(256, 4) void tn_kernel(const float* wsf, int* eidx, float* dnb,
                                                 float* outf, unsigned long long outEidx,
                                                 const void* Xraw, const void* maskp) {
  if (blockIdx.x < NRES/4) topk_body(blockIdx.x, wsf, eidx, dnb, outf, outEidx);
  else                     node_body(blockIdx.x - NRES/4, wsf, Xraw, maskp, outf);
}

// ---- kernel C: edge features -> K=23 matvec (64 edges/block) -> LN -> f32 out ----
// pos(16 rows) and chains(16 rows) folded into P2[dd][128]/C2[k][128] lookups at
// acc-init; matvec runs only RBF(16)+orientation(7). W rows 16..38 from global (L1-hot).
__global__ __launch_bounds__(256) void edge_kernel(const float* wsf, const int* eidx,
                                                   const void* Xraw, const void* maskp,
                                                   const void* residx, const void* chains,
                                                   float* outf, unsigned long long outE) {
  __shared__ float F[KD][EPB];     // 5888 B — RBF rows 0..15, orient rows 16..22
  __shared__ int   ddL[EPB];       // 256 B — positional bucket per edge
  __shared__ int   skL[EPB];       // 256 B — chain-pair class per edge (0=same)
  const bool isbf = probe_bf(maskp);
  const int icmode = probe_int(residx);
  const int t = threadIdx.x;
  const int g = t & 63, sq = t >> 6;
  const int e = blockIdx.x * EPB + g;
  const int row = e / NK;
  const int b = row / NL, i = row % NL;
  const float D = wsf[WOFF_DNB + e];
  if (sq == 0) {  // wave 0: discrete features -> LDS (waves 1-3 skip the gathers)
    const int j = eidx[e];
    const int ri = geti(residx, b*NL + i, icmode), rj = geti(residx, b*NL + j, icmode);
    int dd = rj - ri + 32;
    dd = dd < 0 ? 0 : (dd > 64 ? 64 : dd);
    const int ci = geti(chains, b*NL + i, icmode), cj = geti(chains, b*NL + j, icmode);
    ddL[g] = dd;
    skL[g] = (ci == cj) ? 0 : 1;
  }
  #pragma unroll
  for (int u = 0; u < 4; ++u) {   // RBF rows: wave sq fills rows sq*4..sq*4+3
    const int s = sq*4 + u;
    float mu = (float)(2.0 + s * (20.0 / 15.0));
    float tt = (D - mu) / 1.25f;
    F[s][g] = expf(-(tt*tt));
  }
  if (g < 16) {  // dU + quaternion (rows 16..22): wave sq handles edges sq*16..sq*16+15
    const int gq = sq*16 + g;
    const int eq = blockIdx.x * EPB + gq;
    const int rowq = eq / NK;
    const int bq = rowq / NL;
    const int jq = eidx[eq];
    const float* Oi = wsf + WOFF_O + (size_t)rowq*9;
    const float* Oj = wsf + WOFF_O + ((size_t)(bq*NL + jq))*9;
    const int ci_ = rowq*12 + 3, cj_ = (bq*NL + jq)*12 + 3;
    float dx = loadf(Xraw, cj_+0, isbf) - loadf(Xraw, ci_+0, isbf);
    float dy = loadf(Xraw, cj_+1, isbf) - loadf(Xraw, ci_+1, isbf);
    float dz = loadf(Xraw, cj_+2, isbf) - loadf(Xraw, ci_+2, isbf);
    float du0 = Oi[0]*dx + Oi[1]*dy + Oi[2]*dz;
    float du1 = Oi[3]*dx + Oi[4]*dy + Oi[5]*dz;
    float du2 = Oi[6]*dx + Oi[7]*dy + Oi[8]*dz;
    float n = fmaxf(sqrtf(du0*du0 + du1*du1 + du2*du2), 1e-12f);
    F[16][gq] = du0/n; F[17][gq] = du1/n; F[18][gq] = du2/n;
    float R[3][3];
    #pragma unroll
    for (int a2=0;a2<3;a2++)
      #pragma unroll
      for (int m=0;m<3;m++)
        R[a2][m] = Oi[0*3+a2]*Oj[0*3+m] + Oi[1*3+a2]*Oj[1*3+m] + Oi[2*3+a2]*Oj[2*3+m];
    float mx = 0.5f*sqrtf(fabsf(1.0f + R[0][0] - R[1][1] - R[2][2]));
    float my = 0.5f*sqrtf(fabsf(1.0f - R[0][0] + R[1][1] - R[2][2]));
    float mz = 0.5f*sqrtf(fabsf(1.0f - R[0][0] - R[1][1] + R[2][2]));
    float qx = sgnf(R[2][1]-R[1][2]) * mx;
    float qy = sgnf(R[0][2]-R[2][0]) * my;
    float qz = sgnf(R[1][0]-R[0][1]) * mz;
    float qw = sqrtf(fmaxf(1.0f + R[0][0] + R[1][1] + R[2][2], 0.0f)) / 2.0f;
    float qn = fmaxf(sqrtf(qx*qx + qy*qy + qz*qz + qw*qw), 1e-12f);
    F[19][gq] = qx/qn; F[20][gq] = qy/qn; F[21][gq] = qz/qn; F[22][gq] = qw/qn;
  }
  __syncthreads();
  // phase 2: wave wv -> edges wv*16..wv*16+15; lane owns 4 edges (eg) x 8 cols (cg)
  const int wv = t >> 6, lane = t & 63;
  const int eg = lane >> 4;          // edge sub-group 0..3
  const int cg = lane & 15;          // col group 0..15
  const int ebase = wv*16 + eg*4;    // block-local first edge of this lane's 4
  const int c0 = cg*8;               // first col of this lane's 8
  const float4* W4 = (const float4*)(wsf + WOFF_WEDGE);   // [55][32] float4, L1-hot
  float acc[4][8];
  #pragma unroll
  for (int qq=0;qq<4;qq++){
    const int ed = ebase + qq;
    const float* p2 = wsf + WOFF_P2 + ddL[ed]*128 + c0;   // pos+bias fold (L1/L2, 33 KB)
    const float* c2 = wsf + WOFF_C2 + skL[ed]*128 + c0;   // chains fold (L1, 1 KB)
    float4 pA = *(const float4*)p2, pB = *(const float4*)(p2+4);
    float4 cA = *(const float4*)c2, cB = *(const float4*)(c2+4);
    acc[qq][0]=pA.x+cA.x; acc[qq][1]=pA.y+cA.y; acc[qq][2]=pA.z+cA.z; acc[qq][3]=pA.w+cA.w;
    acc[qq][4]=pB.x+cB.x; acc[qq][5]=pB.y+cB.y; acc[qq][6]=pB.z+cB.z; acc[qq][7]=pB.w+cB.w;
  }
  for (int d = 0; d < KD; ++d) {
    float4 f  = *(const float4*)&F[d][ebase];   // 1 ds_read_b128, 4-addr broadcast
    float4 wa = W4[(16+d)*32 + cg*2];           // W rows 16..38, cols c0..c0+3
    float4 wb = W4[(16+d)*32 + cg*2 + 1];       // cols c0+4..c0+7
    #pragma unroll
    for (int qq=0;qq<4;qq++){
      float fq = (qq==0)?f.x:(qq==1)?f.y:(qq==2)?f.z:f.w;
      acc[qq][0] = fmaf(fq, wa.x, acc[qq][0]);
      acc[qq][1] = fmaf(fq, wa.y, acc[qq][1]);
      acc[qq][2] = fmaf(fq, wa.z, acc[qq][2]);
      acc[qq][3] = fmaf(fq, wa.w, acc[qq][3]);
      acc[qq][4] = fmaf(fq, wb.x, acc[qq][4]);
      acc[qq][5] = fmaf(fq, wb.y, acc[qq][5]);
      acc[qq][6] = fmaf(fq, wb.z, acc[qq][6]);
      acc[qq][7] = fmaf(fq, wb.w, acc[qq][7]);
    }
  }
  const float4 geA = *(const float4*)(wsf + WOFF_GE + c0);
  const float4 geB = *(const float4*)(wsf + WOFF_GE + c0 + 4);
  const float4 bnA = *(const float4*)(wsf + WOFF_BNE + c0);
  const float4 bnB = *(const float4*)(wsf + WOFF_BNE + c0 + 4);
  #pragma unroll
  for (int qq=0;qq<4;qq++){
    float s = ((acc[qq][0]+acc[qq][1])+(acc[qq][2]+acc[qq][3]))
            + ((acc[qq][4]+acc[qq][5])+(acc[qq][6]+acc[qq][7]));
    // butterfly over the 16-lane col group (lanes share eg; xor<16 stays in group)
    s += __shfl_xor(s, 1, 64); s += __shfl_xor(s, 2, 64);
    s += __shfl_xor(s, 4, 64); s += __shfl_xor(s, 8, 64);
    float mu_ = s * (1.0f/128.0f);
    float dv[8];
    #pragma unroll
    for (int jj=0;jj<8;jj++) dv[jj] = acc[qq][jj] - mu_;
    float v = ((dv[0]*dv[0]+dv[1]*dv[1])+(dv[2]*dv[2]+dv[3]*dv[3]))
            + ((dv[4]*dv[4]+dv[5]*dv[5])+(dv[6]*dv[6]+dv[7]*dv[7]));
    v += __shfl_xor(v, 1, 64); v += __shfl_xor(v, 2, 64);
    v += __shfl_xor(v, 4, 64); v += __shfl_xor(v, 8, 64);
    float inv = 1.0f / sqrtf(v * (1.0f/128.0f) + 1e-5f);
    float4 oA, oB;
    oA.x = dv[0]*inv*geA.x + bnA.x; oA.y = dv[1]*inv*geA.y + bnA.y;
    oA.z = dv[2]*inv*geA.z + bnA.z; oA.w = dv[3]*inv*geA.w + bnA.w;
    oB.x = dv[4]*inv*geB.x + bnB.x; oB.y = dv[5]*inv*geB.y + bnB.y;
    oB.z = dv[6]*inv*geB.z + bnB.z; oB.w = dv[7]*inv*geB.w + bnB.w;
    float* op = outf + outE + (size_t)(blockIdx.x*EPB + ebase + qq)*128 + c0;
    *(float4*)op       = oA;
    *(float4*)(op + 4) = oB;
  }
}

extern "C" void kernel_launch(void* const* d_in, const int* in_sizes, int n_in,
                              void* d_out, int out_size, void* d_ws, size_t ws_size,
                              hipStream_t stream) {
  float* wsf = (float*)d_ws;
  int* eidx = (int*)(wsf + WOFF_EIDX);
  float* dnb = wsf + WOFF_DNB;
  float* outf = (float*)d_out;   // output is FLOAT32 (confirmed r4)
  const void* Xraw = d_in[0];
  const void* maskp = d_in[1];

  unsigned long long outEidx = (unsigned long long)out_size - NEDGE;
  unsigned long long outE    = outEidx - (unsigned long long)NEDGE*128;

  ConvArgs ca;
  const int fsz[12]  = {1040, 16, 32, 16, 384, 128, 7040, 128, 128, 128, 128, 128};
  const int foff[12] = {WOFF_WPE, WOFF_BPE, WOFF_WCH, WOFF_BCH, WOFF_WNODE, WOFF_BNODE,
                        WOFF_WEDGE, WOFF_BEDGE, WOFF_GN, WOFF_BNN, WOFF_GE, WOFF_BNE};
  for (int q = 0; q < 12; ++q) { ca.src[q] = d_in[4 + q]; ca.off[q] = foff[q]; ca.sz[q] = fsz[q]; }
  ca.maskp = maskp;

  pf_kernel<<<106, 256, 0, stream>>>(ca, Xraw, wsf);
  tn_kernel<<<NRES/4 + NRES/4, 256, 0, stream>>>(wsf, eidx, dnb, outf, outEidx, Xraw, maskp);
  edge_kernel<<<NEDGE/EPB, 256, 0, stream>>>(wsf, eidx, Xraw, maskp, d_in[2], d_in[3], outf, outE);
}